// Round 1
// baseline (692.467 us; speedup 1.0000x reference)
//
#include <hip/hip_runtime.h>
#include <stdint.h>

// ---------------------------------------------------------------------------
// ModifiedSelfAttention (Wan block): QKV GEMM -> RMSNorm+RoPE -> flash attn -> O GEMM
// All matmuls in bf16 MFMA (16x16x32, guide-verified layouts), fp32 accumulate.
// ---------------------------------------------------------------------------

#define DIM   1536
#define S_TOT 3744
#define NHEAD 12
#define HD    128

using short8 = __attribute__((ext_vector_type(8))) short;   // 8 bf16 (4 VGPRs)
using f32x4  = __attribute__((ext_vector_type(4))) float;   // MFMA C/D
using f32x2  = __attribute__((ext_vector_type(2))) float;

__device__ __forceinline__ unsigned short f2bf(float f) {
  unsigned u = __builtin_bit_cast(unsigned, f);
  u += 0x7fffu + ((u >> 16) & 1u);     // RNE
  return (unsigned short)(u >> 16);
}

// async global->LDS, 16B per lane. LDS dest must be wave-uniform base + lane*16.
__device__ __forceinline__ void gl_lds16(const void* g, void* l) {
  auto gp = (const __attribute__((address_space(1))) unsigned int*)g;
  auto lp = (__attribute__((address_space(3))) unsigned int*)(uintptr_t)l;
  __builtin_amdgcn_global_load_lds(gp, lp, 16, 0, 0);
}

// ---------------------------------------------------------------------------
// fp32 -> bf16 contiguous convert (all our arrays are multiple-of-4 elements)
// ---------------------------------------------------------------------------
__global__ __launch_bounds__(256) void cvt_kernel(const float* __restrict__ src,
                                                  unsigned short* __restrict__ dst,
                                                  int n4) {
  int idx = blockIdx.x * 256 + threadIdx.x;
  if (idx < n4) {
    float4 v = ((const float4*)src)[idx];
    ushort4 o;
    o.x = f2bf(v.x); o.y = f2bf(v.y); o.z = f2bf(v.z); o.w = f2bf(v.w);
    ((ushort4*)dst)[idx] = o;
  }
}

// ---------------------------------------------------------------------------
// NT GEMM: C[m,n] = sum_k A[m,k]*W[n,k] + bias[n].  A:[M,1536] bf16, W:[1536,1536] bf16.
// m97 structure: 128x128 tile, BK=32, 4 waves each 64x64 (4x4 MFMA tiles),
// global_load_lds width=16 staging, 2 barriers per K-iter.
// mode 0: fp32 out, mode 1: bf16 out.
// ---------------------------------------------------------------------------
__device__ __forceinline__ void gemm_body(const unsigned short* __restrict__ A,
                                          const unsigned short* __restrict__ W,
                                          const float* __restrict__ bias,
                                          float* __restrict__ outF,
                                          unsigned short* __restrict__ outB,
                                          int M, int mode) {
  constexpr int K = DIM, N = DIM;
  __shared__ unsigned short As[128 * 32];
  __shared__ unsigned short Ws[128 * 32];
  int tid = threadIdx.x;
  int w = tid >> 6, lane = tid & 63;
  int wr = w >> 1, wc = w & 1, q4 = lane >> 4, ql = lane & 15;
  int m0 = blockIdx.y * 128, n0 = blockIdx.x * 128;

  f32x4 acc[4][4];
  const f32x4 zero4 = {0.f, 0.f, 0.f, 0.f};
#pragma unroll
  for (int i = 0; i < 4; i++)
#pragma unroll
    for (int j = 0; j < 4; j++) acc[i][j] = zero4;

  for (int k0 = 0; k0 < K; k0 += 32) {
    __syncthreads();   // previous compute's LDS reads done
#pragma unroll
    for (int r = 0; r < 2; r++) {
      int idx = r * 256 + tid;
      int row = idx >> 2, ch = idx & 3;
      int am = m0 + row; am = (am < M) ? am : (M - 1);   // clamp M-tail
      gl_lds16(A + (size_t)am * K + k0 + ch * 8, &As[idx * 8]);
      gl_lds16(W + (size_t)(n0 + row) * K + k0 + ch * 8, &Ws[idx * 8]);
    }
    __syncthreads();   // drains vmcnt -> LDS valid
    short8 af[4], wf[4];
#pragma unroll
    for (int i = 0; i < 4; i++)
      af[i] = *(const short8*)&As[(wr * 64 + i * 16 + ql) * 32 + q4 * 8];
#pragma unroll
    for (int j = 0; j < 4; j++)
      wf[j] = *(const short8*)&Ws[(wc * 64 + j * 16 + ql) * 32 + q4 * 8];
#pragma unroll
    for (int i = 0; i < 4; i++)
#pragma unroll
      for (int j = 0; j < 4; j++)
        acc[i][j] = __builtin_amdgcn_mfma_f32_16x16x32_bf16(af[i], wf[j], acc[i][j], 0, 0, 0);
  }

  float bb[4];
#pragma unroll
  for (int j = 0; j < 4; j++) bb[j] = bias[n0 + wc * 64 + j * 16 + ql];
  // C/D layout: col = lane&15, row = (lane>>4)*4 + reg  [m89/m91 verified]
#pragma unroll
  for (int i = 0; i < 4; i++) {
#pragma unroll
    for (int rg = 0; rg < 4; rg++) {
      int row = m0 + wr * 64 + i * 16 + q4 * 4 + rg;
      if (row < M) {
#pragma unroll
        for (int j = 0; j < 4; j++) {
          int col = n0 + wc * 64 + j * 16 + ql;
          float v = acc[i][j][rg] + bb[j];
          if (mode == 0) outF[(size_t)row * N + col] = v;
          else           outB[(size_t)row * N + col] = f2bf(v);
        }
      }
    }
  }
}

__global__ __launch_bounds__(256) void gemm_qkv_kernel(
    const unsigned short* __restrict__ xb,
    const unsigned short* __restrict__ wqb, const unsigned short* __restrict__ wkb,
    const unsigned short* __restrict__ wvb,
    const float* __restrict__ bq, const float* __restrict__ bk, const float* __restrict__ bv,
    float* __restrict__ Yq, float* __restrict__ Yk, unsigned short* __restrict__ Vb) {
  int z = blockIdx.z;
  const unsigned short* W = (z == 0) ? wqb : ((z == 1) ? wkb : wvb);
  const float* bias       = (z == 0) ? bq  : ((z == 1) ? bk  : bv);
  float* outF             = (z == 0) ? Yq  : Yk;
  gemm_body(xb, W, bias, outF, Vb, S_TOT, (z == 2) ? 1 : 0);
}

__global__ __launch_bounds__(256) void gemm_out_kernel(
    const unsigned short* __restrict__ AO, const unsigned short* __restrict__ wob,
    const float* __restrict__ bo, float* __restrict__ out) {
  gemm_body(AO, wob, bo, out, nullptr, S_TOT, 0);
}

// ---------------------------------------------------------------------------
// RMSNorm (over full 1536) + RoPE (3D grid F=3,H=26,W=48; splits 22/21/21) -> bf16
// One block per sequence row; thread t owns float2 pairs p = t, t+256, t+512.
// ---------------------------------------------------------------------------
__global__ __launch_bounds__(256) void normrope_kernel(
    const float* __restrict__ Yq, const float* __restrict__ Yk,
    const float* __restrict__ gq, const float* __restrict__ gk,
    const float* __restrict__ freqs,
    unsigned short* __restrict__ Qb, unsigned short* __restrict__ Kb) {
  int s = blockIdx.x;
  int tid = threadIdx.x;
  int w = tid >> 6, lane = tid & 63;
  const f32x2* yq2 = (const f32x2*)(Yq + (size_t)s * DIM);
  const f32x2* yk2 = (const f32x2*)(Yk + (size_t)s * DIM);
  f32x2 vq[3], vk[3];
  float ssq = 0.f, ssk = 0.f;
#pragma unroll
  for (int r = 0; r < 3; r++) {
    int p = tid + 256 * r;
    vq[r] = yq2[p]; vk[r] = yk2[p];
    ssq += vq[r].x * vq[r].x + vq[r].y * vq[r].y;
    ssk += vk[r].x * vk[r].x + vk[r].y * vk[r].y;
  }
#pragma unroll
  for (int d = 1; d < 64; d <<= 1) {
    ssq += __shfl_xor(ssq, d);
    ssk += __shfl_xor(ssk, d);
  }
  __shared__ float rq[4], rk[4];
  if (lane == 0) { rq[w] = ssq; rk[w] = ssk; }
  __syncthreads();
  float tq = rq[0] + rq[1] + rq[2] + rq[3];
  float tk = rk[0] + rk[1] + rk[2] + rk[3];
  float invq = rsqrtf(tq * (1.f / DIM) + 1e-6f);
  float invk = rsqrtf(tk * (1.f / DIM) + 1e-6f);

  int fi = s / (26 * 48);
  int hi = (s / 48) % 26;
  int wi = s % 48;
#pragma unroll
  for (int r = 0; r < 3; r++) {
    int p = tid + 256 * r;          // global pair index, c = p % 64 within head
    int c = p & 63;
    int frow = (c < 22) ? fi : ((c < 43) ? hi : wi);
    float ang = freqs[frow * 64 + c];
    float sn, cs;
    __sincosf(ang, &sn, &cs);
    {
      float a = vq[r].x * invq * gq[2 * p];
      float b = vq[r].y * invq * gq[2 * p + 1];
      ushort2 o; o.x = f2bf(a * cs - b * sn); o.y = f2bf(a * sn + b * cs);
      ((ushort2*)Qb)[(size_t)s * (DIM / 2) + p] = o;
    }
    {
      float a = vk[r].x * invk * gk[2 * p];
      float b = vk[r].y * invk * gk[2 * p + 1];
      ushort2 o; o.x = f2bf(a * cs - b * sn); o.y = f2bf(a * sn + b * cs);
      ((ushort2*)Kb)[(size_t)s * (DIM / 2) + p] = o;
    }
  }
}

// ---------------------------------------------------------------------------
// V transpose: Vb [S,1536] bf16 -> Vt [1536,S] bf16 (64x64 LDS tiles)
// ---------------------------------------------------------------------------
__global__ __launch_bounds__(256) void vtrans_kernel(const unsigned short* __restrict__ Vb,
                                                     unsigned short* __restrict__ Vt) {
  int d0 = blockIdx.x * 64, s0 = blockIdx.y * 64;
  __shared__ unsigned short t[64][65];
  int tid = threadIdx.x;
#pragma unroll
  for (int r = 0; r < 4; r++) {
    int idx = r * 256 + tid;
    int sr = idx >> 4, c4 = (idx & 15) * 4;
    ushort4 v; v.x = v.y = v.z = v.w = 0;
    int s = s0 + sr;
    if (s < S_TOT) v = *(const ushort4*)(Vb + (size_t)s * DIM + d0 + c4);
    t[sr][c4 + 0] = v.x; t[sr][c4 + 1] = v.y; t[sr][c4 + 2] = v.z; t[sr][c4 + 3] = v.w;
  }
  __syncthreads();
#pragma unroll
  for (int r = 0; r < 4; r++) {
    int idx = r * 256 + tid;
    int dr = idx >> 4, s4 = (idx & 15) * 4;
    if (s0 + s4 < S_TOT) {      // S_TOT%4==0 -> chunk fully valid or fully OOB
      ushort4 v;
      v.x = t[s4 + 0][dr]; v.y = t[s4 + 1][dr]; v.z = t[s4 + 2][dr]; v.w = t[s4 + 3][dr];
      *(ushort4*)(Vt + (size_t)(d0 + dr) * S_TOT + s0 + s4) = v;
    }
  }
}

// ---------------------------------------------------------------------------
// Flash attention. Block = 4 waves x 16 q-rows = 64 q; K-tiles of 64 keys.
// Trick: compute S^T = K_tile . Q^T so softmax row index = lane&15 -> per-lane
// online-softmax state, only 2 shfl_xor per tile. P -> LDS (padded) -> A-frags for PV.
// Vt is pre-transposed so PV B-frags are contiguous 16B LDS reads.
// ---------------------------------------------------------------------------
__global__ __launch_bounds__(256) void attn_kernel(
    const unsigned short* __restrict__ Qb, const unsigned short* __restrict__ Kb,
    const unsigned short* __restrict__ Vt, unsigned short* __restrict__ AO,
    const int* __restrict__ seq_lens) {
  int h = blockIdx.y;
  int tid = threadIdx.x;
  int w = tid >> 6, lane = tid & 63;
  int q4 = lane >> 4, ql = lane & 15;
  int seqlen = seq_lens[0]; if (seqlen > S_TOT) seqlen = S_TOT;

  __shared__ unsigned short Kl[64 * 136];    // [64 keys][128 d], stride 136 (pad 8)
  __shared__ unsigned short Vl[128 * 72];    // [128 d][64 keys], stride 72 (pad 8)
  __shared__ unsigned short Pl[4][16 * 72];  // per-wave P [16 q][64 keys], stride 72
  __shared__ float stat[4][16];              // per-wave alpha / 1/l broadcast

  int qw0 = blockIdx.x * 64 + w * 16;
  bool wact = (qw0 < S_TOT);
  int qrow = qw0 + ql; if (qrow > S_TOT - 1) qrow = S_TOT - 1;

  // Q B-frags (B[k=d][n=q]: n=lane&15 -> q, k=(lane>>4)*8+j), direct from global
  short8 qf[4];
#pragma unroll
  for (int ks = 0; ks < 4; ks++)
    qf[ks] = *(const short8*)(Qb + (size_t)qrow * DIM + h * HD + ks * 32 + q4 * 8);

  f32x4 o[8];
  const f32x4 zero4 = {0.f, 0.f, 0.f, 0.f};
#pragma unroll
  for (int nt = 0; nt < 8; nt++) o[nt] = zero4;
  float m_run = -3.0e38f, l_run = 0.f;
  const float sm_scale = 0.08838834764831845f;   // 128^-0.5

  for (int kt = 0; kt < (S_TOT + 63) / 64; kt++) {
    int k0 = kt * 64;
    __syncthreads();
    // stage K tile: 64 rows x 16 chunks of 16B
#pragma unroll
    for (int r = 0; r < 4; r++) {
      int idx = r * 256 + tid;
      int row = idx >> 4, ch = idx & 15;
      int key = k0 + row;
      short8 v = {0, 0, 0, 0, 0, 0, 0, 0};
      if (key < S_TOT) v = *(const short8*)(Kb + (size_t)key * DIM + h * HD + ch * 8);
      *(short8*)&Kl[row * 136 + ch * 8] = v;
    }
    // stage V^T tile: 128 rows x 8 chunks of 16B
#pragma unroll
    for (int r = 0; r < 4; r++) {
      int idx = r * 256 + tid;
      int row = idx >> 3, ch = idx & 7;
      int kc = k0 + ch * 8;
      short8 v = {0, 0, 0, 0, 0, 0, 0, 0};
      if (kc < S_TOT) v = *(const short8*)(Vt + (size_t)(h * HD + row) * S_TOT + kc);
      *(short8*)&Vl[row * 72 + ch * 8] = v;
    }
    __syncthreads();
    if (!wact) continue;   // wave-uniform; barriers above reached by all

    // S^T[key][q] = sum_d K[key][d]*Q[q][d] ; A = K-frag (m=key), B = qf
    f32x4 st[4];
#pragma unroll
    for (int mt = 0; mt < 4; mt++) {
      f32x4 a = zero4;
#pragma unroll
      for (int ks = 0; ks < 4; ks++) {
        short8 kf = *(const short8*)&Kl[(mt * 16 + ql) * 136 + ks * 32 + q4 * 8];
        a = __builtin_amdgcn_mfma_f32_16x16x32_bf16(kf, qf[ks], a, 0, 0, 0);
      }
      st[mt] = a;
    }
    // per-lane q = ql; lane holds 16 keys (mt, q4*4+rg)
    float sc[16];
    float mloc = -3.0e38f;
#pragma unroll
    for (int mt = 0; mt < 4; mt++)
#pragma unroll
      for (int rg = 0; rg < 4; rg++) {
        int key = k0 + mt * 16 + q4 * 4 + rg;
        float v = st[mt][rg] * sm_scale;
        v = (key < seqlen) ? v : -3.0e38f;
        sc[mt * 4 + rg] = v;
        mloc = fmaxf(mloc, v);
      }
    mloc = fmaxf(mloc, __shfl_xor(mloc, 16));
    mloc = fmaxf(mloc, __shfl_xor(mloc, 32));
    float mnew = fmaxf(m_run, mloc);
    float alpha = __expf(m_run - mnew);
    m_run = mnew;
    float lloc = 0.f;
#pragma unroll
    for (int mt = 0; mt < 4; mt++)
#pragma unroll
      for (int rg = 0; rg < 4; rg++) {
        int keyl = mt * 16 + q4 * 4 + rg;
        float p = (k0 + keyl < seqlen) ? __expf(sc[mt * 4 + rg] - m_run) : 0.f;
        lloc += p;
        Pl[w][ql * 72 + keyl] = f2bf(p);
      }
    lloc += __shfl_xor(lloc, 16);
    lloc += __shfl_xor(lloc, 32);
    l_run = l_run * alpha + lloc;
    if (lane < 16) stat[w][lane] = alpha;   // alpha for q = qw0+lane
    float ar[4];
#pragma unroll
    for (int rg = 0; rg < 4; rg++) ar[rg] = stat[w][q4 * 4 + rg];  // O row = q4*4+rg
#pragma unroll
    for (int nt = 0; nt < 8; nt++)
#pragma unroll
      for (int rg = 0; rg < 4; rg++) o[nt][rg] *= ar[rg];
    // O[q][d] += P.V : A = P (m=q=lane&15), B = V^T rows (n=d=lane&15 within nt)
#pragma unroll
    for (int ks2 = 0; ks2 < 2; ks2++) {
      short8 pa = *(const short8*)&Pl[w][ql * 72 + ks2 * 32 + q4 * 8];
#pragma unroll
      for (int nt = 0; nt < 8; nt++) {
        short8 vb = *(const short8*)&Vl[(nt * 16 + ql) * 72 + ks2 * 32 + q4 * 8];
        o[nt] = __builtin_amdgcn_mfma_f32_16x16x32_bf16(pa, vb, o[nt], 0, 0, 0);
      }
    }
  }

  if (wact) {
    float linv = 1.0f / l_run;
    if (lane < 16) stat[w][lane] = linv;
    #pragma unroll
    for (int rg = 0; rg < 4; rg++) {
      int row = qw0 + q4 * 4 + rg;
      if (row < S_TOT) {
        float il = stat[w][q4 * 4 + rg];
#pragma unroll
        for (int nt = 0; nt < 8; nt++)
          AO[(size_t)row * DIM + h * HD + nt * 16 + ql] = f2bf(o[nt][rg] * il);
      }
    }
  }
}

// ---------------------------------------------------------------------------
extern "C" void kernel_launch(void* const* d_in, const int* in_sizes, int n_in,
                              void* d_out, int out_size, void* d_ws, size_t ws_size,
                              hipStream_t stream) {
  const float* x    = (const float*)d_in[0];
  const float* wq   = (const float*)d_in[1];
  const float* bq   = (const float*)d_in[2];
  const float* wk   = (const float*)d_in[3];
  const float* bk   = (const float*)d_in[4];
  const float* wv   = (const float*)d_in[5];
  const float* bv   = (const float*)d_in[6];
  const float* wo   = (const float*)d_in[7];
  const float* bo   = (const float*)d_in[8];
  const float* gq   = (const float*)d_in[9];
  const float* gk   = (const float*)d_in[10];
  const float* freqs = (const float*)d_in[11];
  const int*   seq  = (const int*)d_in[12];

  char* ws = (char*)d_ws;
  const size_t SZ_X = (size_t)S_TOT * DIM * 2;   // bf16 [S,DIM]
  const size_t SZ_W = (size_t)DIM * DIM * 2;     // bf16 [DIM,DIM]
  const size_t SZ_Y = (size_t)S_TOT * DIM * 4;   // fp32 [S,DIM]

  unsigned short* xb  = (unsigned short*)(ws);
  unsigned short* wqb = (unsigned short*)(ws + SZ_X);
  unsigned short* wkb = (unsigned short*)(ws + SZ_X + SZ_W);
  unsigned short* wvb = (unsigned short*)(ws + SZ_X + 2 * SZ_W);
  unsigned short* wob = (unsigned short*)(ws + SZ_X + 3 * SZ_W);
  float*          Yq  = (float*)(ws + SZ_X + 4 * SZ_W);
  float*          Yk  = (float*)(ws + SZ_X + 4 * SZ_W + SZ_Y);
  unsigned short* Vb  = (unsigned short*)(ws + SZ_X + 4 * SZ_W + 2 * SZ_Y);
  unsigned short* Qb  = (unsigned short*)(ws + SZ_X + 4 * SZ_W + 2 * SZ_Y + SZ_X);
  unsigned short* Kb  = (unsigned short*)(ws + SZ_X + 4 * SZ_W + 2 * SZ_Y + 2 * SZ_X);
  unsigned short* Vt  = (unsigned short*)(ws + SZ_X + 4 * SZ_W + 2 * SZ_Y + 3 * SZ_X);
  unsigned short* AO  = (unsigned short*)(ws + SZ_X + 4 * SZ_W + 2 * SZ_Y + 4 * SZ_X);
  // total ws use ~134 MB

  int nx4 = S_TOT * DIM / 4, nw4 = DIM * DIM / 4;
  cvt_kernel<<<dim3((nx4 + 255) / 256), 256, 0, stream>>>(x, xb, nx4);
  cvt_kernel<<<dim3((nw4 + 255) / 256), 256, 0, stream>>>(wq, wqb, nw4);
  cvt_kernel<<<dim3((nw4 + 255) / 256), 256, 0, stream>>>(wk, wkb, nw4);
  cvt_kernel<<<dim3((nw4 + 255) / 256), 256, 0, stream>>>(wv, wvb, nw4);
  cvt_kernel<<<dim3((nw4 + 255) / 256), 256, 0, stream>>>(wo, wob, nw4);

  gemm_qkv_kernel<<<dim3(DIM / 128, (S_TOT + 127) / 128, 3), 256, 0, stream>>>(
      xb, wqb, wkb, wvb, bq, bk, bv, Yq, Yk, Vb);

  normrope_kernel<<<dim3(S_TOT), 256, 0, stream>>>(Yq, Yk, gq, gk, freqs, Qb, Kb);

  vtrans_kernel<<<dim3(DIM / 64, (S_TOT + 63) / 64), 256, 0, stream>>>(Vb, Vt);

  attn_kernel<<<dim3((S_TOT + 63) / 64, NHEAD), 256, 0, stream>>>(Qb, Kb, Vt, AO, seq);

  gemm_out_kernel<<<dim3(DIM / 128, (S_TOT + 127) / 128), 256, 0, stream>>>(
      AO, wob, bo, (float*)d_out);
}

// Round 2
// 477.509 us; speedup vs baseline: 1.4502x; 1.4502x over previous
//
#include <hip/hip_runtime.h>
#include <stdint.h>

// ---------------------------------------------------------------------------
// ModifiedSelfAttention (Wan block): QKV GEMM -> RMSNorm+RoPE -> flash attn -> O GEMM
// All matmuls in bf16 MFMA (16x16x32, guide-verified layouts), fp32 accumulate.
// R1: attn restructured - 32q/wave (2 B-frag halves), global_load_lds staging
// with XOR chunk swizzle (no pad, 2-way = free), packed b64 P-writes, merged cvt.
// ---------------------------------------------------------------------------

#define DIM   1536
#define S_TOT 3744
#define NHEAD 12
#define HD    128

using short8 = __attribute__((ext_vector_type(8))) short;   // 8 bf16 (4 VGPRs)
using f32x4  = __attribute__((ext_vector_type(4))) float;   // MFMA C/D
using f32x2  = __attribute__((ext_vector_type(2))) float;

__device__ __forceinline__ unsigned short f2bf(float f) {
  unsigned u = __builtin_bit_cast(unsigned, f);
  u += 0x7fffu + ((u >> 16) & 1u);     // RNE
  return (unsigned short)(u >> 16);
}

// async global->LDS, 16B per lane. LDS dest must be wave-uniform base + lane*16.
__device__ __forceinline__ void gl_lds16(const void* g, void* l) {
  auto gp = (const __attribute__((address_space(1))) unsigned int*)g;
  auto lp = (__attribute__((address_space(3))) unsigned int*)(uintptr_t)l;
  __builtin_amdgcn_global_load_lds(gp, lp, 16, 0, 0);
}

// ---------------------------------------------------------------------------
// fp32 -> bf16 convert, all 5 arrays in one launch
// ---------------------------------------------------------------------------
#define NX4 (S_TOT * DIM / 4)
#define NW4 (DIM * DIM / 4)
__global__ __launch_bounds__(256) void cvt5_kernel(
    const float* __restrict__ x, const float* __restrict__ wq,
    const float* __restrict__ wk, const float* __restrict__ wv,
    const float* __restrict__ wo,
    unsigned short* __restrict__ xb, unsigned short* __restrict__ wqb,
    unsigned short* __restrict__ wkb, unsigned short* __restrict__ wvb,
    unsigned short* __restrict__ wob) {
  int gid = blockIdx.x * 256 + threadIdx.x;
  const float* src; unsigned short* dst; int off;
  if (gid < NX4)                { src = x;  dst = xb;  off = gid; }
  else if (gid < NX4 + NW4)     { src = wq; dst = wqb; off = gid - NX4; }
  else if (gid < NX4 + 2 * NW4) { src = wk; dst = wkb; off = gid - NX4 - NW4; }
  else if (gid < NX4 + 3 * NW4) { src = wv; dst = wvb; off = gid - NX4 - 2 * NW4; }
  else if (gid < NX4 + 4 * NW4) { src = wo; dst = wob; off = gid - NX4 - 3 * NW4; }
  else return;
  float4 v = ((const float4*)src)[off];
  ushort4 o;
  o.x = f2bf(v.x); o.y = f2bf(v.y); o.z = f2bf(v.z); o.w = f2bf(v.w);
  ((ushort4*)dst)[off] = o;
}

// ---------------------------------------------------------------------------
// NT GEMM: C[m,n] = sum_k A[m,k]*W[n,k] + bias[n]. m97 structure (unchanged, proven).
// ---------------------------------------------------------------------------
__device__ __forceinline__ void gemm_body(const unsigned short* __restrict__ A,
                                          const unsigned short* __restrict__ W,
                                          const float* __restrict__ bias,
                                          float* __restrict__ outF,
                                          unsigned short* __restrict__ outB,
                                          int M, int mode) {
  constexpr int K = DIM, N = DIM;
  __shared__ unsigned short As[128 * 32];
  __shared__ unsigned short Ws[128 * 32];
  int tid = threadIdx.x;
  int w = tid >> 6, lane = tid & 63;
  int wr = w >> 1, wc = w & 1, q4 = lane >> 4, ql = lane & 15;
  int m0 = blockIdx.y * 128, n0 = blockIdx.x * 128;

  f32x4 acc[4][4];
  const f32x4 zero4 = {0.f, 0.f, 0.f, 0.f};
#pragma unroll
  for (int i = 0; i < 4; i++)
#pragma unroll
    for (int j = 0; j < 4; j++) acc[i][j] = zero4;

  for (int k0 = 0; k0 < K; k0 += 32) {
    __syncthreads();
#pragma unroll
    for (int r = 0; r < 2; r++) {
      int idx = r * 256 + tid;
      int row = idx >> 2, ch = idx & 3;
      int am = m0 + row; am = (am < M) ? am : (M - 1);
      gl_lds16(A + (size_t)am * K + k0 + ch * 8, &As[idx * 8]);
      gl_lds16(W + (size_t)(n0 + row) * K + k0 + ch * 8, &Ws[idx * 8]);
    }
    __syncthreads();
    short8 af[4], wf[4];
#pragma unroll
    for (int i = 0; i < 4; i++)
      af[i] = *(const short8*)&As[(wr * 64 + i * 16 + ql) * 32 + q4 * 8];
#pragma unroll
    for (int j = 0; j < 4; j++)
      wf[j] = *(const short8*)&Ws[(wc * 64 + j * 16 + ql) * 32 + q4 * 8];
#pragma unroll
    for (int i = 0; i < 4; i++)
#pragma unroll
      for (int j = 0; j < 4; j++)
        acc[i][j] = __builtin_amdgcn_mfma_f32_16x16x32_bf16(af[i], wf[j], acc[i][j], 0, 0, 0);
  }

  float bb[4];
#pragma unroll
  for (int j = 0; j < 4; j++) bb[j] = bias[n0 + wc * 64 + j * 16 + ql];
#pragma unroll
  for (int i = 0; i < 4; i++) {
#pragma unroll
    for (int rg = 0; rg < 4; rg++) {
      int row = m0 + wr * 64 + i * 16 + q4 * 4 + rg;
      if (row < M) {
#pragma unroll
        for (int j = 0; j < 4; j++) {
          int col = n0 + wc * 64 + j * 16 + ql;
          float v = acc[i][j][rg] + bb[j];
          if (mode == 0) outF[(size_t)row * N + col] = v;
          else           outB[(size_t)row * N + col] = f2bf(v);
        }
      }
    }
  }
}

__global__ __launch_bounds__(256) void gemm_qkv_kernel(
    const unsigned short* __restrict__ xb,
    const unsigned short* __restrict__ wqb, const unsigned short* __restrict__ wkb,
    const unsigned short* __restrict__ wvb,
    const float* __restrict__ bq, const float* __restrict__ bk, const float* __restrict__ bv,
    float* __restrict__ Yq, float* __restrict__ Yk, unsigned short* __restrict__ Vb) {
  int z = blockIdx.z;
  const unsigned short* W = (z == 0) ? wqb : ((z == 1) ? wkb : wvb);
  const float* bias       = (z == 0) ? bq  : ((z == 1) ? bk  : bv);
  float* outF             = (z == 0) ? Yq  : Yk;
  gemm_body(xb, W, bias, outF, Vb, S_TOT, (z == 2) ? 1 : 0);
}

__global__ __launch_bounds__(256) void gemm_out_kernel(
    const unsigned short* __restrict__ AO, const unsigned short* __restrict__ wob,
    const float* __restrict__ bo, float* __restrict__ out) {
  gemm_body(AO, wob, bo, out, nullptr, S_TOT, 0);
}

// ---------------------------------------------------------------------------
// RMSNorm + RoPE (unchanged, proven)
// ---------------------------------------------------------------------------
__global__ __launch_bounds__(256) void normrope_kernel(
    const float* __restrict__ Yq, const float* __restrict__ Yk,
    const float* __restrict__ gq, const float* __restrict__ gk,
    const float* __restrict__ freqs,
    unsigned short* __restrict__ Qb, unsigned short* __restrict__ Kb) {
  int s = blockIdx.x;
  int tid = threadIdx.x;
  int w = tid >> 6, lane = tid & 63;
  const f32x2* yq2 = (const f32x2*)(Yq + (size_t)s * DIM);
  const f32x2* yk2 = (const f32x2*)(Yk + (size_t)s * DIM);
  f32x2 vq[3], vk[3];
  float ssq = 0.f, ssk = 0.f;
#pragma unroll
  for (int r = 0; r < 3; r++) {
    int p = tid + 256 * r;
    vq[r] = yq2[p]; vk[r] = yk2[p];
    ssq += vq[r].x * vq[r].x + vq[r].y * vq[r].y;
    ssk += vk[r].x * vk[r].x + vk[r].y * vk[r].y;
  }
#pragma unroll
  for (int d = 1; d < 64; d <<= 1) {
    ssq += __shfl_xor(ssq, d);
    ssk += __shfl_xor(ssk, d);
  }
  __shared__ float rq[4], rk[4];
  if (lane == 0) { rq[w] = ssq; rk[w] = ssk; }
  __syncthreads();
  float tq = rq[0] + rq[1] + rq[2] + rq[3];
  float tk = rk[0] + rk[1] + rk[2] + rk[3];
  float invq = rsqrtf(tq * (1.f / DIM) + 1e-6f);
  float invk = rsqrtf(tk * (1.f / DIM) + 1e-6f);

  int fi = s / (26 * 48);
  int hi = (s / 48) % 26;
  int wi = s % 48;
#pragma unroll
  for (int r = 0; r < 3; r++) {
    int p = tid + 256 * r;
    int c = p & 63;
    int frow = (c < 22) ? fi : ((c < 43) ? hi : wi);
    float ang = freqs[frow * 64 + c];
    float sn, cs;
    __sincosf(ang, &sn, &cs);
    {
      float a = vq[r].x * invq * gq[2 * p];
      float b = vq[r].y * invq * gq[2 * p + 1];
      ushort2 o; o.x = f2bf(a * cs - b * sn); o.y = f2bf(a * sn + b * cs);
      ((ushort2*)Qb)[(size_t)s * (DIM / 2) + p] = o;
    }
    {
      float a = vk[r].x * invk * gk[2 * p];
      float b = vk[r].y * invk * gk[2 * p + 1];
      ushort2 o; o.x = f2bf(a * cs - b * sn); o.y = f2bf(a * sn + b * cs);
      ((ushort2*)Kb)[(size_t)s * (DIM / 2) + p] = o;
    }
  }
}

// ---------------------------------------------------------------------------
// V transpose (unchanged, proven)
// ---------------------------------------------------------------------------
__global__ __launch_bounds__(256) void vtrans_kernel(const unsigned short* __restrict__ Vb,
                                                     unsigned short* __restrict__ Vt) {
  int d0 = blockIdx.x * 64, s0 = blockIdx.y * 64;
  __shared__ unsigned short t[64][65];
  int tid = threadIdx.x;
#pragma unroll
  for (int r = 0; r < 4; r++) {
    int idx = r * 256 + tid;
    int sr = idx >> 4, c4 = (idx & 15) * 4;
    ushort4 v; v.x = v.y = v.z = v.w = 0;
    int s = s0 + sr;
    if (s < S_TOT) v = *(const ushort4*)(Vb + (size_t)s * DIM + d0 + c4);
    t[sr][c4 + 0] = v.x; t[sr][c4 + 1] = v.y; t[sr][c4 + 2] = v.z; t[sr][c4 + 3] = v.w;
  }
  __syncthreads();
#pragma unroll
  for (int r = 0; r < 4; r++) {
    int idx = r * 256 + tid;
    int dr = idx >> 4, s4 = (idx & 15) * 4;
    if (s0 + s4 < S_TOT) {
      ushort4 v;
      v.x = t[s4 + 0][dr]; v.y = t[s4 + 1][dr]; v.z = t[s4 + 2][dr]; v.w = t[s4 + 3][dr];
      *(ushort4*)(Vt + (size_t)(d0 + dr) * S_TOT + s0 + s4) = v;
    }
  }
}

// ---------------------------------------------------------------------------
// Flash attention v2. Block = 2 waves x 32 q = 64 q; K-tiles of 64 keys.
// S^T = K.Q^T (softmax row = lane&15, per-lane state x2 halves).
// K/V staged via global_load_lds DMA with XOR chunk swizzle:
//   Kl slot(row,c) holds K chunk c^(row&15)  (row*128 elem, 16 chunks of 8)
//   Vl slot(row,c) holds Vt chunk c^(row&7)  (row*64 elem, 8 chunks of 8)
// Readers recompute the swizzle -> 2 lanes/bank-group = conflict-free (m136).
// P written as packed b64 (4 consecutive keys per lane).
// ---------------------------------------------------------------------------
__global__ __launch_bounds__(128, 2) void attn_kernel(
    const unsigned short* __restrict__ Qb, const unsigned short* __restrict__ Kb,
    const unsigned short* __restrict__ Vt, unsigned short* __restrict__ AO,
    const int* __restrict__ seq_lens) {
  int h = blockIdx.y;
  int tid = threadIdx.x;                  // 0..127
  int w = tid >> 6, lane = tid & 63;
  int q4 = lane >> 4, ql = lane & 15;
  int seqlen = seq_lens[0]; if (seqlen > S_TOT) seqlen = S_TOT;

  __shared__ unsigned short Kl[64 * 128];   // 16 KB, swizzled
  __shared__ unsigned short Vl[128 * 64];   // 16 KB, swizzled
  __shared__ unsigned short Pl[2][32 * 72]; // 9 KB, per-wave P [32 q][64 k], pad 8
  __shared__ float stat[2][32];

  int q0 = blockIdx.x * 64 + w * 32;
  bool wact = (q0 < S_TOT);

  // Q B-frags, both 16-q halves (n=lane&15 -> q, k=(lane>>4)*8+j)
  short8 qf[2][4];
#pragma unroll
  for (int qh = 0; qh < 2; qh++) {
    int qrow = q0 + qh * 16 + ql; if (qrow > S_TOT - 1) qrow = S_TOT - 1;
#pragma unroll
    for (int ks = 0; ks < 4; ks++)
      qf[qh][ks] = *(const short8*)(Qb + (size_t)qrow * DIM + h * HD + ks * 32 + q4 * 8);
  }

  f32x4 o[2][8];
  const f32x4 zero4 = {0.f, 0.f, 0.f, 0.f};
#pragma unroll
  for (int qh = 0; qh < 2; qh++)
#pragma unroll
    for (int nt = 0; nt < 8; nt++) o[qh][nt] = zero4;
  float m_run[2] = {-3.0e38f, -3.0e38f}, l_run[2] = {0.f, 0.f};
  const float sm_scale = 0.08838834764831845f;   // 128^-0.5

  const size_t hoff = (size_t)h * HD;
  // thread-invariant staging offsets (hoisted by compiler)
  // K: idx = r*128+tid -> row=idx>>4, c=idx&15, fetch chunk g=c^(row&15)
  // V: idx = r*128+tid -> row=idx>>3, c=idx&7,  fetch chunk g=c^(row&7)

  for (int kt = 0; kt < (S_TOT + 63) / 64; kt++) {
    int k0 = kt * 64;
    __syncthreads();                         // prev iter's LDS reads done
    {
      const unsigned short* kseg = Kb + (size_t)k0 * DIM + hoff;
#pragma unroll
      for (int r = 0; r < 8; r++) {
        int idx = r * 128 + tid;
        int row = idx >> 4, c = idx & 15;
        int g = c ^ (row & 15);
        // rows beyond S_TOT read garbage inside ws; masked in softmax (finite)
        gl_lds16(kseg + (size_t)row * DIM + g * 8, &Kl[idx * 8]);
      }
      int kmax = S_TOT - 8 - k0;             // clamp V key-chunk start
#pragma unroll
      for (int r = 0; r < 8; r++) {
        int idx = r * 128 + tid;
        int row = idx >> 3, c = idx & 7;
        int g = c ^ (row & 7);
        int kc = g * 8; if (kc > kmax) kc = kmax;
        gl_lds16(Vt + (hoff + row) * S_TOT + k0 + kc, &Vl[idx * 8]);
      }
    }
    __syncthreads();                         // DMA drained -> LDS valid
    if (!wact) continue;

    // ---- QK^T: S^T[key][q], kf shared across the two q-halves ----
    f32x4 st[4][2];
#pragma unroll
    for (int mt = 0; mt < 4; mt++) {
      st[mt][0] = zero4; st[mt][1] = zero4;
#pragma unroll
      for (int ks = 0; ks < 4; ks++) {
        int c = (ks * 4 + q4) ^ ql;          // swizzle (row&15 == ql)
        short8 kf = *(const short8*)&Kl[(mt * 16 + ql) * 128 + c * 8];
        st[mt][0] = __builtin_amdgcn_mfma_f32_16x16x32_bf16(kf, qf[0][ks], st[mt][0], 0, 0, 0);
        st[mt][1] = __builtin_amdgcn_mfma_f32_16x16x32_bf16(kf, qf[1][ks], st[mt][1], 0, 0, 0);
      }
    }

    // ---- online softmax per half; packed b64 P-writes ----
#pragma unroll
    for (int qh = 0; qh < 2; qh++) {
      float sc[16];
      float mloc = -3.0e38f;
#pragma unroll
      for (int mt = 0; mt < 4; mt++)
#pragma unroll
        for (int rg = 0; rg < 4; rg++) {
          int key = k0 + mt * 16 + q4 * 4 + rg;
          float v = st[mt][qh][rg] * sm_scale;
          v = (key < seqlen) ? v : -3.0e38f;
          sc[mt * 4 + rg] = v;
          mloc = fmaxf(mloc, v);
        }
      mloc = fmaxf(mloc, __shfl_xor(mloc, 16));
      mloc = fmaxf(mloc, __shfl_xor(mloc, 32));
      float mnew = fmaxf(m_run[qh], mloc);
      float alpha = __expf(m_run[qh] - mnew);
      m_run[qh] = mnew;
      float lloc = 0.f;
#pragma unroll
      for (int mt = 0; mt < 4; mt++) {
        ushort4 pk;
        float p0 = (k0 + mt * 16 + q4 * 4 + 0 < seqlen) ? __expf(sc[mt * 4 + 0] - mnew) : 0.f;
        float p1 = (k0 + mt * 16 + q4 * 4 + 1 < seqlen) ? __expf(sc[mt * 4 + 1] - mnew) : 0.f;
        float p2 = (k0 + mt * 16 + q4 * 4 + 2 < seqlen) ? __expf(sc[mt * 4 + 2] - mnew) : 0.f;
        float p3 = (k0 + mt * 16 + q4 * 4 + 3 < seqlen) ? __expf(sc[mt * 4 + 3] - mnew) : 0.f;
        lloc += p0 + p1 + p2 + p3;
        pk.x = f2bf(p0); pk.y = f2bf(p1); pk.z = f2bf(p2); pk.w = f2bf(p3);
        *(ushort4*)&Pl[w][(qh * 16 + ql) * 72 + mt * 16 + q4 * 4] = pk;
      }
      lloc += __shfl_xor(lloc, 16);
      lloc += __shfl_xor(lloc, 32);
      l_run[qh] = l_run[qh] * alpha + lloc;
      if (lane < 16) stat[w][qh * 16 + lane] = alpha;
    }

    // ---- rescale O by alpha (row q = q4*4+rg within each half) ----
    float ar[2][4];
#pragma unroll
    for (int qh = 0; qh < 2; qh++)
#pragma unroll
      for (int rg = 0; rg < 4; rg++) ar[qh][rg] = stat[w][qh * 16 + q4 * 4 + rg];
#pragma unroll
    for (int qh = 0; qh < 2; qh++)
#pragma unroll
      for (int nt = 0; nt < 8; nt++)
#pragma unroll
        for (int rg = 0; rg < 4; rg++) o[qh][nt][rg] *= ar[qh][rg];

    // ---- PV: O[q][d] += P.V^T ; vb shared across the two q-halves ----
#pragma unroll
    for (int ks2 = 0; ks2 < 2; ks2++) {
      short8 pa0 = *(const short8*)&Pl[w][(0 * 16 + ql) * 72 + ks2 * 32 + q4 * 8];
      short8 pa1 = *(const short8*)&Pl[w][(1 * 16 + ql) * 72 + ks2 * 32 + q4 * 8];
#pragma unroll
      for (int nt = 0; nt < 8; nt++) {
        int c = (ks2 * 4 + q4) ^ (ql & 7);   // swizzle (row&7 == ql&7)
        short8 vb = *(const short8*)&Vl[(nt * 16 + ql) * 64 + c * 8];
        o[0][nt] = __builtin_amdgcn_mfma_f32_16x16x32_bf16(pa0, vb, o[0][nt], 0, 0, 0);
        o[1][nt] = __builtin_amdgcn_mfma_f32_16x16x32_bf16(pa1, vb, o[1][nt], 0, 0, 0);
      }
    }
  }

  if (wact) {
    if (lane < 16) {
      stat[w][lane]      = 1.0f / l_run[0];
      stat[w][16 + lane] = 1.0f / l_run[1];
    }
#pragma unroll
    for (int qh = 0; qh < 2; qh++) {
#pragma unroll
      for (int rg = 0; rg < 4; rg++) {
        int row = q0 + qh * 16 + q4 * 4 + rg;
        if (row < S_TOT) {
          float il = stat[w][qh * 16 + q4 * 4 + rg];
#pragma unroll
          for (int nt = 0; nt < 8; nt++)
            AO[(size_t)row * DIM + h * HD + nt * 16 + ql] = f2bf(o[qh][nt][rg] * il);
        }
      }
    }
  }
}

// ---------------------------------------------------------------------------
extern "C" void kernel_launch(void* const* d_in, const int* in_sizes, int n_in,
                              void* d_out, int out_size, void* d_ws, size_t ws_size,
                              hipStream_t stream) {
  const float* x    = (const float*)d_in[0];
  const float* wq   = (const float*)d_in[1];
  const float* bq   = (const float*)d_in[2];
  const float* wk   = (const float*)d_in[3];
  const float* bk   = (const float*)d_in[4];
  const float* wv   = (const float*)d_in[5];
  const float* bv   = (const float*)d_in[6];
  const float* wo   = (const float*)d_in[7];
  const float* bo   = (const float*)d_in[8];
  const float* gq   = (const float*)d_in[9];
  const float* gk   = (const float*)d_in[10];
  const float* freqs = (const float*)d_in[11];
  const int*   seq  = (const int*)d_in[12];

  char* ws = (char*)d_ws;
  const size_t SZ_X = (size_t)S_TOT * DIM * 2;   // bf16 [S,DIM]
  const size_t SZ_W = (size_t)DIM * DIM * 2;     // bf16 [DIM,DIM]
  const size_t SZ_Y = (size_t)S_TOT * DIM * 4;   // fp32 [S,DIM]

  unsigned short* xb  = (unsigned short*)(ws);
  unsigned short* wqb = (unsigned short*)(ws + SZ_X);
  unsigned short* wkb = (unsigned short*)(ws + SZ_X + SZ_W);
  unsigned short* wvb = (unsigned short*)(ws + SZ_X + 2 * SZ_W);
  unsigned short* wob = (unsigned short*)(ws + SZ_X + 3 * SZ_W);
  float*          Yq  = (float*)(ws + SZ_X + 4 * SZ_W);
  float*          Yk  = (float*)(ws + SZ_X + 4 * SZ_W + SZ_Y);
  unsigned short* Vb  = (unsigned short*)(ws + SZ_X + 4 * SZ_W + 2 * SZ_Y);
  unsigned short* Qb  = (unsigned short*)(ws + SZ_X + 4 * SZ_W + 2 * SZ_Y + SZ_X);
  unsigned short* Kb  = (unsigned short*)(ws + SZ_X + 4 * SZ_W + 2 * SZ_Y + 2 * SZ_X);
  unsigned short* Vt  = (unsigned short*)(ws + SZ_X + 4 * SZ_W + 2 * SZ_Y + 3 * SZ_X);
  unsigned short* AO  = (unsigned short*)(ws + SZ_X + 4 * SZ_W + 2 * SZ_Y + 4 * SZ_X);

  int total4 = NX4 + 4 * NW4;
  cvt5_kernel<<<dim3((total4 + 255) / 256), 256, 0, stream>>>(
      x, wq, wk, wv, wo, xb, wqb, wkb, wvb, wob);

  gemm_qkv_kernel<<<dim3(DIM / 128, (S_TOT + 127) / 128, 3), 256, 0, stream>>>(
      xb, wqb, wkb, wvb, bq, bk, bv, Yq, Yk, Vb);

  normrope_kernel<<<dim3(S_TOT), 256, 0, stream>>>(Yq, Yk, gq, gk, freqs, Qb, Kb);

  vtrans_kernel<<<dim3(DIM / 64, (S_TOT + 63) / 64), 256, 0, stream>>>(Vb, Vt);

  attn_kernel<<<dim3((S_TOT + 63) / 64, NHEAD), 128, 0, stream>>>(Qb, Kb, Vt, AO, seq);

  gemm_out_kernel<<<dim3(DIM / 128, (S_TOT + 127) / 128), 256, 0, stream>>>(
      AO, wob, bo, (float*)d_out);
}